// Round 2
// baseline (539.669 us; speedup 1.0000x reference)
//
#include <hip/hip_runtime.h>

// Problem geometry (fixed by the reference): [B=2, D=160, H=192, W=160, C=3]
constexpr int D_ = 160;
constexpr int H_ = 192;
constexpr int W_ = 160;
constexpr int NVOX = D_ * H_ * W_;   // per-batch voxel count = 4,915,200
constexpr int BATCH = 2;
constexpr int W4 = W_ / 4;           // 40 groups of 4 voxels along z

// 12-byte corner read: 3 channels of one d1 voxel in ONE global_load_dwordx3.
struct F3 { float a, b, c; };

// out = trilinear(d1, grid + d2) + d2, neurite-style clipping:
//   loc0c = clip(floor(loc), 0, dim-1); loc1c = clip(floor(loc)+1, 0, dim-1)
//   w_floor = clip(loc1c - loc, 0, 1);  w_ceil = 1 - w_floor
__global__ __launch_bounds__(256) void compose_kernel(
    const float* __restrict__ d1,
    const float* __restrict__ d2,
    float* __restrict__ out)
{
    // One thread = 4 consecutive z-voxels. Grid is exact: 2*NVOX/4 / 256 = 9600.
    int gid = blockIdx.x * 256 + threadIdx.x;

    // gid = ((b*D + x)*H + y)*W4 + zg
    int zg = gid % W4;
    int t  = gid / W4;
    int y  = t % H_;
    int t2 = t / H_;
    int x  = t2 % D_;
    int b  = t2 / D_;
    int z0 = zg * 4;

    const float* __restrict__ d1b = d1 + (size_t)b * (NVOX * 3);

    // d2 for 4 voxels: 12 contiguous floats, 16B-aligned (gid*48).
    const float4* __restrict__ d2v = (const float4*)(d2 + (size_t)gid * 12);
    float4 q0 = d2v[0];
    float4 q1 = d2v[1];
    float4 q2 = d2v[2];
    float dbuf[12] = { q0.x, q0.y, q0.z, q0.w,
                       q1.x, q1.y, q1.z, q1.w,
                       q2.x, q2.y, q2.z, q2.w };

    float obuf[12];

    const float fx_ = (float)x;
    const float fy_ = (float)y;

    #pragma unroll
    for (int j = 0; j < 4; ++j) {
        const float dxv = dbuf[3 * j + 0];
        const float dyv = dbuf[3 * j + 1];
        const float dzv = dbuf[3 * j + 2];

        const float lx = fx_ + dxv;
        const float ly = fy_ + dyv;
        const float lz = (float)(z0 + j) + dzv;

        // X axis
        float fx  = floorf(lx);
        float x0f = fminf(fmaxf(fx,       0.f), (float)(D_ - 1));
        float x1f = fminf(fmaxf(fx + 1.f, 0.f), (float)(D_ - 1));
        float wx0 = fminf(fmaxf(x1f - lx, 0.f), 1.f);
        float wx1 = 1.f - wx0;
        int ix0 = (int)x0f, ix1 = (int)x1f;

        // Y axis
        float fy  = floorf(ly);
        float y0f = fminf(fmaxf(fy,       0.f), (float)(H_ - 1));
        float y1f = fminf(fmaxf(fy + 1.f, 0.f), (float)(H_ - 1));
        float wy0 = fminf(fmaxf(y1f - ly, 0.f), 1.f);
        float wy1 = 1.f - wy0;
        int iy0 = (int)y0f, iy1 = (int)y1f;

        // Z axis
        float fz  = floorf(lz);
        float z0f = fminf(fmaxf(fz,       0.f), (float)(W_ - 1));
        float z1f = fminf(fmaxf(fz + 1.f, 0.f), (float)(W_ - 1));
        float wz0 = fminf(fmaxf(z1f - lz, 0.f), 1.f);
        float wz1 = 1.f - wz0;
        int iz0 = (int)z0f, iz1 = (int)z1f;

        // Row bases for the 4 (x,y) combos
        int b00 = (ix0 * H_ + iy0) * W_;
        int b01 = (ix0 * H_ + iy1) * W_;
        int b10 = (ix1 * H_ + iy0) * W_;
        int b11 = (ix1 * H_ + iy1) * W_;

        const float wxy00 = wx0 * wy0;
        const float wxy01 = wx0 * wy1;
        const float wxy10 = wx1 * wy0;
        const float wxy11 = wx1 * wy1;

        // 8 corner gathers, each ONE 12B load (dwordx3).
        F3 c000 = *(const F3*)(d1b + (size_t)(b00 + iz0) * 3);
        F3 c001 = *(const F3*)(d1b + (size_t)(b00 + iz1) * 3);
        F3 c010 = *(const F3*)(d1b + (size_t)(b01 + iz0) * 3);
        F3 c011 = *(const F3*)(d1b + (size_t)(b01 + iz1) * 3);
        F3 c100 = *(const F3*)(d1b + (size_t)(b10 + iz0) * 3);
        F3 c101 = *(const F3*)(d1b + (size_t)(b10 + iz1) * 3);
        F3 c110 = *(const F3*)(d1b + (size_t)(b11 + iz0) * 3);
        F3 c111 = *(const F3*)(d1b + (size_t)(b11 + iz1) * 3);

        const float w000 = wxy00 * wz0, w001 = wxy00 * wz1;
        const float w010 = wxy01 * wz0, w011 = wxy01 * wz1;
        const float w100 = wxy10 * wz0, w101 = wxy10 * wz1;
        const float w110 = wxy11 * wz0, w111 = wxy11 * wz1;

        float acc0, acc1, acc2;
        acc0 = w000 * c000.a; acc1 = w000 * c000.b; acc2 = w000 * c000.c;
        acc0 = fmaf(w001, c001.a, acc0); acc1 = fmaf(w001, c001.b, acc1); acc2 = fmaf(w001, c001.c, acc2);
        acc0 = fmaf(w010, c010.a, acc0); acc1 = fmaf(w010, c010.b, acc1); acc2 = fmaf(w010, c010.c, acc2);
        acc0 = fmaf(w011, c011.a, acc0); acc1 = fmaf(w011, c011.b, acc1); acc2 = fmaf(w011, c011.c, acc2);
        acc0 = fmaf(w100, c100.a, acc0); acc1 = fmaf(w100, c100.b, acc1); acc2 = fmaf(w100, c100.c, acc2);
        acc0 = fmaf(w101, c101.a, acc0); acc1 = fmaf(w101, c101.b, acc1); acc2 = fmaf(w101, c101.c, acc2);
        acc0 = fmaf(w110, c110.a, acc0); acc1 = fmaf(w110, c110.b, acc1); acc2 = fmaf(w110, c110.c, acc2);
        acc0 = fmaf(w111, c111.a, acc0); acc1 = fmaf(w111, c111.b, acc1); acc2 = fmaf(w111, c111.c, acc2);

        obuf[3 * j + 0] = acc0 + dxv;
        obuf[3 * j + 1] = acc1 + dyv;
        obuf[3 * j + 2] = acc2 + dzv;
    }

    // Store 4 voxels = 12 contiguous floats as 3 float4 (16B-aligned).
    float4* __restrict__ ov = (float4*)(out + (size_t)gid * 12);
    ov[0] = make_float4(obuf[0], obuf[1], obuf[2],  obuf[3]);
    ov[1] = make_float4(obuf[4], obuf[5], obuf[6],  obuf[7]);
    ov[2] = make_float4(obuf[8], obuf[9], obuf[10], obuf[11]);
}

extern "C" void kernel_launch(void* const* d_in, const int* in_sizes, int n_in,
                              void* d_out, int out_size, void* d_ws, size_t ws_size,
                              hipStream_t stream)
{
    const float* d1 = (const float*)d_in[0];  // disp_1
    const float* d2 = (const float*)d_in[1];  // disp_2
    float* out = (float*)d_out;

    const int groups = BATCH * NVOX / 4;      // 2,457,600 threads
    const int blocks = groups / 256;          // 9,600 blocks (exact)

    compose_kernel<<<dim3(blocks), dim3(256), 0, stream>>>(d1, d2, out);
}

// Round 3
// 442.270 us; speedup vs baseline: 1.2202x; 1.2202x over previous
//
#include <hip/hip_runtime.h>

// Problem geometry (fixed by the reference): [B=2, D=160, H=192, W=160, C=3]
constexpr int D_ = 160;
constexpr int H_ = 192;
constexpr int W_ = 160;
constexpr int NVOX = D_ * H_ * W_;   // per-batch voxel count = 4,915,200
constexpr int BATCH = 2;

// 12-byte packed vec: one d1/d2/out voxel (3 floats) in ONE dwordx3 access.
struct F3 { float a, b, c; };

// out = trilinear(d1, grid + d2) + d2, neurite-style clipping:
//   loc0c = clip(floor(loc), 0, dim-1); loc1c = clip(floor(loc)+1, 0, dim-1)
//   w_floor = clip(loc1c - loc, 0, 1);  w_ceil = 1 - w_floor
//
// 1 voxel/thread (round-1 mapping: tight 12B lane stride for gathers → best
// L1/L2 locality, FETCH ~290MB), but all memory as fused 12B dwordx3:
// 1 d2 load + 8 corner gathers + 1 out store = 10 VMEM instrs (was 30).
__global__ __launch_bounds__(256) void compose_kernel(
    const float* __restrict__ d1,
    const float* __restrict__ d2,
    float* __restrict__ out)
{
    int idx = blockIdx.x * 256 + threadIdx.x;

    int b = idx / NVOX;
    int v = idx - b * NVOX;
    int z = v % W_;
    int t = v / W_;
    int y = t % H_;
    int x = t / H_;

    const float* __restrict__ d1b = d1 + (size_t)b * (NVOX * 3);

    // d2 for this voxel: one 12B load.
    F3 dv = *(const F3*)(d2 + (size_t)idx * 3);
    const float dxv = dv.a, dyv = dv.b, dzv = dv.c;

    const float lx = (float)x + dxv;
    const float ly = (float)y + dyv;
    const float lz = (float)z + dzv;

    // X axis
    float fx  = floorf(lx);
    float x0f = fminf(fmaxf(fx,       0.f), (float)(D_ - 1));
    float x1f = fminf(fmaxf(fx + 1.f, 0.f), (float)(D_ - 1));
    float wx0 = fminf(fmaxf(x1f - lx, 0.f), 1.f);
    float wx1 = 1.f - wx0;
    int ix0 = (int)x0f, ix1 = (int)x1f;

    // Y axis
    float fy  = floorf(ly);
    float y0f = fminf(fmaxf(fy,       0.f), (float)(H_ - 1));
    float y1f = fminf(fmaxf(fy + 1.f, 0.f), (float)(H_ - 1));
    float wy0 = fminf(fmaxf(y1f - ly, 0.f), 1.f);
    float wy1 = 1.f - wy0;
    int iy0 = (int)y0f, iy1 = (int)y1f;

    // Z axis
    float fz  = floorf(lz);
    float z0f = fminf(fmaxf(fz,       0.f), (float)(W_ - 1));
    float z1f = fminf(fmaxf(fz + 1.f, 0.f), (float)(W_ - 1));
    float wz0 = fminf(fmaxf(z1f - lz, 0.f), 1.f);
    float wz1 = 1.f - wz0;
    int iz0 = (int)z0f, iz1 = (int)z1f;

    // Row bases for the 4 (x,y) combos
    int b00 = (ix0 * H_ + iy0) * W_;
    int b01 = (ix0 * H_ + iy1) * W_;
    int b10 = (ix1 * H_ + iy0) * W_;
    int b11 = (ix1 * H_ + iy1) * W_;

    const float wxy00 = wx0 * wy0;
    const float wxy01 = wx0 * wy1;
    const float wxy10 = wx1 * wy0;
    const float wxy11 = wx1 * wy1;

    // 8 corner gathers, each ONE 12B load (dwordx3). All independent → 8-deep MLP.
    F3 c000 = *(const F3*)(d1b + (size_t)(b00 + iz0) * 3);
    F3 c001 = *(const F3*)(d1b + (size_t)(b00 + iz1) * 3);
    F3 c010 = *(const F3*)(d1b + (size_t)(b01 + iz0) * 3);
    F3 c011 = *(const F3*)(d1b + (size_t)(b01 + iz1) * 3);
    F3 c100 = *(const F3*)(d1b + (size_t)(b10 + iz0) * 3);
    F3 c101 = *(const F3*)(d1b + (size_t)(b10 + iz1) * 3);
    F3 c110 = *(const F3*)(d1b + (size_t)(b11 + iz0) * 3);
    F3 c111 = *(const F3*)(d1b + (size_t)(b11 + iz1) * 3);

    const float w000 = wxy00 * wz0, w001 = wxy00 * wz1;
    const float w010 = wxy01 * wz0, w011 = wxy01 * wz1;
    const float w100 = wxy10 * wz0, w101 = wxy10 * wz1;
    const float w110 = wxy11 * wz0, w111 = wxy11 * wz1;

    float acc0, acc1, acc2;
    acc0 = w000 * c000.a; acc1 = w000 * c000.b; acc2 = w000 * c000.c;
    acc0 = fmaf(w001, c001.a, acc0); acc1 = fmaf(w001, c001.b, acc1); acc2 = fmaf(w001, c001.c, acc2);
    acc0 = fmaf(w010, c010.a, acc0); acc1 = fmaf(w010, c010.b, acc1); acc2 = fmaf(w010, c010.c, acc2);
    acc0 = fmaf(w011, c011.a, acc0); acc1 = fmaf(w011, c011.b, acc1); acc2 = fmaf(w011, c011.c, acc2);
    acc0 = fmaf(w100, c100.a, acc0); acc1 = fmaf(w100, c100.b, acc1); acc2 = fmaf(w100, c100.c, acc2);
    acc0 = fmaf(w101, c101.a, acc0); acc1 = fmaf(w101, c101.b, acc1); acc2 = fmaf(w101, c101.c, acc2);
    acc0 = fmaf(w110, c110.a, acc0); acc1 = fmaf(w110, c110.b, acc1); acc2 = fmaf(w110, c110.c, acc2);
    acc0 = fmaf(w111, c111.a, acc0); acc1 = fmaf(w111, c111.b, acc1); acc2 = fmaf(w111, c111.c, acc2);

    // One 12B store.
    F3 ov;
    ov.a = acc0 + dxv;
    ov.b = acc1 + dyv;
    ov.c = acc2 + dzv;
    *(F3*)(out + (size_t)idx * 3) = ov;
}

extern "C" void kernel_launch(void* const* d_in, const int* in_sizes, int n_in,
                              void* d_out, int out_size, void* d_ws, size_t ws_size,
                              hipStream_t stream)
{
    const float* d1 = (const float*)d_in[0];  // disp_1
    const float* d2 = (const float*)d_in[1];  // disp_2
    float* out = (float*)d_out;

    const int total = BATCH * NVOX;           // 9,830,400 voxels
    const int blocks = total / 256;           // 38,400 blocks (exact)

    compose_kernel<<<dim3(blocks), dim3(256), 0, stream>>>(d1, d2, out);
}